// Round 9
// baseline (446.382 us; speedup 1.0000x reference)
//
#include <hip/hip_runtime.h>

// ---------------------------------------------------------------------------
// GraphConv x2 (DGL norm='both', self-loops), r9.
// degrees (per-XCD WG-scope atomics) -> norms+scan (+per-XCD cursor bases) ->
// CSR fill (per-XCD WG-scope cursor atomics) ->
// [MFMA-split GEMM+scale -> channel-sliced pull-agg (XCD-L2-resident)] x2
// GEMM: fp32 as bf16 hi/lo split, 3x mfma_f32_16x16x32_bf16.
// r9 NEW: (a) k_fill8 per-XCD cursors (kills device-atomic write-through),
//         (b) agg sliced by 32 channels/block so each XCD's gather footprint
//             is 3.2MB < 4MB L2 (slice = blockIdx % NS matches RR placement).
// ---------------------------------------------------------------------------

typedef __attribute__((ext_vector_type(8))) short short8v;
typedef __attribute__((ext_vector_type(4))) float float4v;
typedef __attribute__((ext_vector_type(2))) _Float16 half2v;

__device__ inline unsigned short f2bf(float x) {
  unsigned u = __float_as_uint(x);
  return (unsigned short)((u + 0x7FFFu + ((u >> 16) & 1u)) >> 16);
}
__device__ inline float bf2f(unsigned short b) {
  return __uint_as_float(((unsigned)b) << 16);
}

// per-XCD degree histograms: cnt[x][0..N) = odeg, cnt[x][N..2N) = ideg.
__global__ __launch_bounds__(256) void k_hist8(const int* __restrict__ src,
                                               const int* __restrict__ dst,
                                               unsigned* __restrict__ cnt,
                                               int N, int E) {
  unsigned xcc;
  asm("s_getreg_b32 %0, hwreg(HW_REG_XCC_ID)" : "=s"(xcc));
  unsigned* my = cnt + (size_t)(xcc & 7) * 2u * (unsigned)N;
  int e = blockIdx.x * 256 + threadIdx.x;
  if (e < E) {
    __hip_atomic_fetch_add(&my[src[e]], 1u, __ATOMIC_RELAXED,
                           __HIP_MEMORY_SCOPE_WORKGROUP);
    __hip_atomic_fetch_add(&my[N + dst[e]], 1u, __ATOMIC_RELAXED,
                           __HIP_MEMORY_SCOPE_WORKGROUP);
  }
}

// sum 8 copies -> degrees; exclusive scan of in-degree; emit rsqrt norms
__global__ __launch_bounds__(256) void k_scan1_norm(
    const unsigned* __restrict__ cnt, int* __restrict__ part,
    int* __restrict__ bsums, float* __restrict__ nsrc,
    float* __restrict__ ndst, int N) {
  __shared__ int s[256];
  int t = threadIdx.x, g = blockIdx.x * 256 + t;
  int od = 0, id = 0;
  if (g < N) {
#pragma unroll
    for (int x = 0; x < 8; ++x) {
      od += cnt[(size_t)x * 2u * (unsigned)N + g];
      id += cnt[(size_t)x * 2u * (unsigned)N + N + g];
    }
    nsrc[g] = rsqrtf((float)(od + 1)); // +1 self-loop, deg>=1
    ndst[g] = rsqrtf((float)(id + 1));
  }
  int v = (g < N) ? id : 0;
  s[t] = v;
  __syncthreads();
  for (int o = 1; o < 256; o <<= 1) {
    int add = (t >= o) ? s[t - o] : 0;
    __syncthreads();
    s[t] += add;
    __syncthreads();
  }
  if (g < N) part[g] = s[t] - v;
  if (t == 255) bsums[blockIdx.x] = s[255];
}

// requires ceil(N/256) <= 256 (N=50000 -> 196 blocks, OK)
__global__ __launch_bounds__(256) void k_scan2(int* __restrict__ bsums, int nb) {
  __shared__ int s[256];
  int t = threadIdx.x;
  int v = (t < nb) ? bsums[t] : 0;
  s[t] = v;
  __syncthreads();
  for (int o = 1; o < 256; o <<= 1) {
    int add = (t >= o) ? s[t - o] : 0;
    __syncthreads();
    s[t] += add;
    __syncthreads();
  }
  if (t < nb) bsums[t] = s[t] - v;
}

// finalize rowptr; init per-XCD cursor bases:
// cursor8[x][v] = rowptr[v] + sum_{y<x} ideg_y[v]
__global__ __launch_bounds__(256) void k_scan3(int* __restrict__ part,
                                               int* __restrict__ cursor8,
                                               const int* __restrict__ bsums,
                                               const unsigned* __restrict__ cnt,
                                               int N, int E) {
  int t = threadIdx.x, g = blockIdx.x * 256 + t;
  if (g < N) {
    int v = part[g] + bsums[blockIdx.x];
    part[g] = v;
    int run = v;
#pragma unroll
    for (int x = 0; x < 8; ++x) {
      cursor8[(size_t)x * N + g] = run;
      run += cnt[(size_t)x * 2u * (unsigned)N + N + g];
    }
  }
  if (g == 0) part[N] = E;
}

// CSR fill with per-XCD cursor copies (WG-scope atomics stay in local L2;
// disjoint ranges per XCD guarantee globally-unique positions).
__global__ __launch_bounds__(256) void k_fill8(const int* __restrict__ src,
                                               const int* __restrict__ dst,
                                               int* __restrict__ cursor8,
                                               int* __restrict__ colidx,
                                               int N, int E) {
  unsigned xcc;
  asm("s_getreg_b32 %0, hwreg(HW_REG_XCC_ID)" : "=s"(xcc));
  int* my = cursor8 + (size_t)(xcc & 7) * N;
  int e = blockIdx.x * 256 + threadIdx.x;
  if (e < E) {
    int s = src[e];
    int p = __hip_atomic_fetch_add(&my[dst[e]], 1, __ATOMIC_RELAXED,
                                   __HIP_MEMORY_SCOPE_WORKGROUP);
    colidx[p] = s;
  }
}

// W [K][NCOL] fp32 -> WtH/WtL [NCOL][K] bf16 (transposed + hi/lo split). K=256.
__global__ __launch_bounds__(256) void k_wsplit(const float* __restrict__ W,
                                                short* __restrict__ WtH,
                                                short* __restrict__ WtL,
                                                int NCOL) {
  const int K = 256;
  int idx = blockIdx.x * 256 + threadIdx.x;
  if (idx >= K * NCOL) return;
  int k = idx & (K - 1);
  int n = idx >> 8;
  float v = W[(size_t)k * NCOL + n];
  unsigned short h = f2bf(v);
  unsigned short l = f2bf(v - bf2f(h));
  WtH[(size_t)n * K + k] = (short)h;
  WtL[(size_t)n * K + k] = (short)l;
}

// out[m,:] = fp16((A[m,:] @ W) * norm[m]); A fp32 [M][256], W pre-split.
// BM=64 rows/block, full NCOL width. bf16 hi/lo split -> 3 MFMA per tile.
template <int NCOL>
__global__ __launch_bounds__(256) void k_gemm_mfma(
    const float* __restrict__ A, const short* __restrict__ WtH,
    const short* __restrict__ WtL, const float* __restrict__ norm,
    _Float16* __restrict__ out, int M) {
  constexpr int K = 256, BM = 64, BK = 32, PAD = 40, NF = NCOL / 16;
  __shared__ short AH[BM][PAD], AL[BM][PAD];
  __shared__ short BH[NCOL][PAD], BL[NCOL][PAD];
  int tid = threadIdx.x;
  int w = tid >> 6, l = tid & 63;
  int lg = l >> 4, ln = l & 15;
  int row0 = blockIdx.x * BM;

  float4v acc[NF];
#pragma unroll
  for (int i = 0; i < NF; ++i) acc[i] = (float4v){0.f, 0.f, 0.f, 0.f};

  int ar = tid >> 2;        // A-stage row 0..63
  int akq = (tid & 3) * 8;  // A-stage k offset 0/8/16/24

  for (int k0 = 0; k0 < K; k0 += BK) {
    // ---- stage A tile: fp32 -> bf16 hi/lo ----
    float av[8];
    int grow = row0 + ar;
    if (grow < M) {
      const float4* ap =
          reinterpret_cast<const float4*>(&A[(size_t)grow * K + k0 + akq]);
      float4 v0 = ap[0], v1 = ap[1];
      av[0] = v0.x; av[1] = v0.y; av[2] = v0.z; av[3] = v0.w;
      av[4] = v1.x; av[5] = v1.y; av[6] = v1.z; av[7] = v1.w;
    } else {
#pragma unroll
      for (int i = 0; i < 8; ++i) av[i] = 0.f;
    }
    short hh[8], ll[8];
#pragma unroll
    for (int i = 0; i < 8; ++i) {
      unsigned short h = f2bf(av[i]);
      hh[i] = (short)h;
      ll[i] = (short)f2bf(av[i] - bf2f(h));
    }
    *reinterpret_cast<short8v*>(&AH[ar][akq]) = *reinterpret_cast<short8v*>(hh);
    *reinterpret_cast<short8v*>(&AL[ar][akq]) = *reinterpret_cast<short8v*>(ll);

    // ---- stage B tile: NCOL rows x 32 k, bf16 pre-split, 16B chunks ----
#pragma unroll
    for (int c = 0; c < NCOL / 64; ++c) {
      int chunk = c * 256 + tid;
      int bn = chunk >> 2, q = (chunk & 3) * 8;
      *reinterpret_cast<short8v*>(&BH[bn][q]) =
          *reinterpret_cast<const short8v*>(&WtH[(size_t)bn * K + k0 + q]);
      *reinterpret_cast<short8v*>(&BL[bn][q]) =
          *reinterpret_cast<const short8v*>(&WtL[(size_t)bn * K + k0 + q]);
    }
    __syncthreads();

    // ---- MFMA ----
    short8v aH = *reinterpret_cast<short8v*>(&AH[w * 16 + ln][lg * 8]);
    short8v aL = *reinterpret_cast<short8v*>(&AL[w * 16 + ln][lg * 8]);
#pragma unroll
    for (int nf = 0; nf < NF; ++nf) {
      short8v bHv = *reinterpret_cast<short8v*>(&BH[nf * 16 + ln][lg * 8]);
      short8v bLv = *reinterpret_cast<short8v*>(&BL[nf * 16 + ln][lg * 8]);
      acc[nf] = __builtin_amdgcn_mfma_f32_16x16x32_bf16(aH, bHv, acc[nf], 0, 0, 0);
      acc[nf] = __builtin_amdgcn_mfma_f32_16x16x32_bf16(aH, bLv, acc[nf], 0, 0, 0);
      acc[nf] = __builtin_amdgcn_mfma_f32_16x16x32_bf16(aL, bHv, acc[nf], 0, 0, 0);
    }
    __syncthreads();
  }

  // ---- epilogue: scale by norm[row], store fp16 ----
  int rbase = row0 + w * 16 + lg * 4;
  float nrm[4];
#pragma unroll
  for (int j = 0; j < 4; ++j)
    nrm[j] = (rbase + j < M) ? norm[rbase + j] : 0.f;
#pragma unroll
  for (int nf = 0; nf < NF; ++nf) {
#pragma unroll
    for (int j = 0; j < 4; ++j) {
      int r = rbase + j;
      if (r < M)
        out[(size_t)r * NCOL + nf * 16 + ln] = (_Float16)(acc[nf][j] * nrm[j]);
    }
  }
}

// Channel-sliced pull aggregation: block owns a 32-channel slice
// (slice = blockIdx % NS -> per-XCD gather footprint N*32*2B = 3.2MB < L2).
// 16 lanes per node, half2 per lane (64B line per edge-gather), fp32 acc.
template <int C>
__global__ __launch_bounds__(256) void k_agg_slice(
    const _Float16* __restrict__ h, const int* __restrict__ rowptr,
    const int* __restrict__ colidx, const float* __restrict__ nd,
    const float* __restrict__ bias, float* __restrict__ out, int N) {
  constexpr int NS = C / 32;
  int slice = blockIdx.x % NS;
  int node = (blockIdx.x / NS) * 16 + (threadIdx.x >> 4);
  int l16 = threadIdx.x & 15;
  if (node >= N) return;
  int ch0 = slice * 32 + l16 * 2;

  const half2v* hv = reinterpret_cast<const half2v*>(h);
  // element index of (row, ch0) in half2 units: (row*C + ch0)/2
  half2v hs = hv[((size_t)node * C + ch0) >> 1]; // self-loop
  float2 acc;
  acc.x = (float)hs[0]; acc.y = (float)hs[1];

  int e0 = rowptr[node], e1 = rowptr[node + 1];
  int e = e0;
  for (; e + 7 < e1; e += 8) {
    int si[8];
#pragma unroll
    for (int i = 0; i < 8; ++i) si[i] = colidx[e + i];
    half2v v[8];
#pragma unroll
    for (int i = 0; i < 8; ++i) v[i] = hv[((size_t)si[i] * C + ch0) >> 1];
#pragma unroll
    for (int i = 0; i < 8; ++i) {
      acc.x += (float)v[i][0];
      acc.y += (float)v[i][1];
    }
  }
  for (; e < e1; ++e) {
    half2v v0 = hv[((size_t)colidx[e] * C + ch0) >> 1];
    acc.x += (float)v0[0];
    acc.y += (float)v0[1];
  }
  float n = nd[node];
  float2 b = *reinterpret_cast<const float2*>(&bias[ch0]);
  float2 r;
  r.x = fmaxf(fmaf(acc.x, n, b.x), 0.f);
  r.y = fmaxf(fmaf(acc.y, n, b.y), 0.f);
  *reinterpret_cast<float2*>(&out[(size_t)node * C + ch0]) = r;
}

extern "C" void kernel_launch(void* const* d_in, const int* in_sizes, int n_in,
                              void* d_out, int out_size, void* d_ws, size_t ws_size,
                              hipStream_t stream) {
  const float* feats = (const float*)d_in[0];
  const int* src = (const int*)d_in[1];
  const int* dst = (const int*)d_in[2];
  const float* W0 = (const float*)d_in[3];
  const float* b0 = (const float*)d_in[4];
  const float* W1 = (const float*)d_in[5];
  const float* b1 = (const float*)d_in[6];
  float* out = (float*)d_out;

  const int IN_CH = 256, HID = 256, OUT_CH = 128;
  int N = in_sizes[0] / IN_CH;
  int E = in_sizes[1];

  char* ws = (char*)d_ws;
  size_t off = 0;
  auto alloc = [&](size_t bytes) -> void* {
    void* p = ws + off;
    off += (bytes + 255) & ~(size_t)255;
    return p;
  };
  _Float16* h0 = (_Float16*)alloc((size_t)N * HID * 2); // layer-0 GEMM out, fp16
  float* x1     = (float*)alloc((size_t)N * HID * 4);   // layer-0 agg out, fp32
  float* nsrc   = (float*)alloc((size_t)N * 4);
  float* ndst   = (float*)alloc((size_t)N * 4);
  unsigned* cnt = (unsigned*)alloc((size_t)8 * 2 * N * 4); // 8 per-XCD copies
  int*   rowptr = (int*)alloc((size_t)(N + 1) * 4);
  int*  cursor8 = (int*)alloc((size_t)8 * N * 4);          // 8 per-XCD cursors
  int*   colidx = (int*)alloc((size_t)E * 4);
  int*   bsums  = (int*)alloc(1024);
  short* w0h    = (short*)alloc((size_t)HID * IN_CH * 2);
  short* w0l    = (short*)alloc((size_t)HID * IN_CH * 2);
  short* w1h    = (short*)alloc((size_t)OUT_CH * HID * 2);
  short* w1l    = (short*)alloc((size_t)OUT_CH * HID * 2);
  _Float16* h1  = h0; // reuse: h0 dead after layer-0 agg

  hipMemsetAsync(cnt, 0, (size_t)8 * 2 * N * 4, stream);

  int nbE = (E + 255) / 256, nbN = (N + 255) / 256;
  k_hist8<<<nbE, 256, 0, stream>>>(src, dst, cnt, N, E);
  k_scan1_norm<<<nbN, 256, 0, stream>>>(cnt, rowptr, bsums, nsrc, ndst, N);
  k_scan2<<<1, 256, 0, stream>>>(bsums, nbN);
  k_scan3<<<nbN, 256, 0, stream>>>(rowptr, cursor8, bsums, cnt, N, E);
  k_fill8<<<nbE, 256, 0, stream>>>(src, dst, cursor8, colidx, N, E);

  // weight transpose + bf16 split (K=256 for both layers)
  k_wsplit<<<(IN_CH * HID) / 256, 256, 0, stream>>>(W0, w0h, w0l, HID);
  k_wsplit<<<(HID * OUT_CH) / 256, 256, 0, stream>>>(W1, w1h, w1l, OUT_CH);

  int gm = (N + 63) / 64;
  int ng = (N + 15) / 16; // node-groups per slice
  k_gemm_mfma<256><<<gm, 256, 0, stream>>>(feats, w0h, w0l, nsrc, h0, N);
  k_agg_slice<256><<<ng * 8, 256, 0, stream>>>(h0, rowptr, colidx, ndst, b0, x1, N);

  k_gemm_mfma<128><<<gm, 256, 0, stream>>>(x1, w1h, w1l, nsrc, h1, N);
  k_agg_slice<128><<<ng * 4, 256, 0, stream>>>(h1, rowptr, colidx, ndst, b1, out, N);
}

// Round 10
// 395.148 us; speedup vs baseline: 1.1297x; 1.1297x over previous
//
#include <hip/hip_runtime.h>

// ---------------------------------------------------------------------------
// GraphConv x2 (DGL norm='both', self-loops), r10.
// degrees (per-XCD WG-scope atomics) -> norms+scan (+per-XCD cursor bases) ->
// CSR fill (per-XCD WG-scope cursor atomics) ->
// [MFMA-split GEMM+scale -> wave-per-node pull-agg (fp16)] x2
// GEMM: fp32/fp16 A as bf16 hi/lo split, 3x mfma_f32_16x16x32_bf16.
// r10: REVERT r9's channel-sliced agg (FETCH didn't drop: blockIdx%8 != XCD
// placement). Keep fill8. NEW: x1 stored fp16 (fp16->bf16 hi/lo is exact) ->
// halves agg256 write + gemm1 A-read traffic.
// ---------------------------------------------------------------------------

typedef __attribute__((ext_vector_type(8))) short short8v;
typedef __attribute__((ext_vector_type(4))) float float4v;
typedef __attribute__((ext_vector_type(8))) _Float16 half8v;
typedef __attribute__((ext_vector_type(4))) _Float16 half4v;
typedef __attribute__((ext_vector_type(2))) _Float16 half2v;

__device__ inline unsigned short f2bf(float x) {
  unsigned u = __float_as_uint(x);
  return (unsigned short)((u + 0x7FFFu + ((u >> 16) & 1u)) >> 16);
}
__device__ inline float bf2f(unsigned short b) {
  return __uint_as_float(((unsigned)b) << 16);
}

// per-XCD degree histograms: cnt[x][0..N) = odeg, cnt[x][N..2N) = ideg.
__global__ __launch_bounds__(256) void k_hist8(const int* __restrict__ src,
                                               const int* __restrict__ dst,
                                               unsigned* __restrict__ cnt,
                                               int N, int E) {
  unsigned xcc;
  asm("s_getreg_b32 %0, hwreg(HW_REG_XCC_ID)" : "=s"(xcc));
  unsigned* my = cnt + (size_t)(xcc & 7) * 2u * (unsigned)N;
  int e = blockIdx.x * 256 + threadIdx.x;
  if (e < E) {
    __hip_atomic_fetch_add(&my[src[e]], 1u, __ATOMIC_RELAXED,
                           __HIP_MEMORY_SCOPE_WORKGROUP);
    __hip_atomic_fetch_add(&my[N + dst[e]], 1u, __ATOMIC_RELAXED,
                           __HIP_MEMORY_SCOPE_WORKGROUP);
  }
}

// sum 8 copies -> degrees; exclusive scan of in-degree; emit rsqrt norms
__global__ __launch_bounds__(256) void k_scan1_norm(
    const unsigned* __restrict__ cnt, int* __restrict__ part,
    int* __restrict__ bsums, float* __restrict__ nsrc,
    float* __restrict__ ndst, int N) {
  __shared__ int s[256];
  int t = threadIdx.x, g = blockIdx.x * 256 + t;
  int od = 0, id = 0;
  if (g < N) {
#pragma unroll
    for (int x = 0; x < 8; ++x) {
      od += cnt[(size_t)x * 2u * (unsigned)N + g];
      id += cnt[(size_t)x * 2u * (unsigned)N + N + g];
    }
    nsrc[g] = rsqrtf((float)(od + 1)); // +1 self-loop, deg>=1
    ndst[g] = rsqrtf((float)(id + 1));
  }
  int v = (g < N) ? id : 0;
  s[t] = v;
  __syncthreads();
  for (int o = 1; o < 256; o <<= 1) {
    int add = (t >= o) ? s[t - o] : 0;
    __syncthreads();
    s[t] += add;
    __syncthreads();
  }
  if (g < N) part[g] = s[t] - v;
  if (t == 255) bsums[blockIdx.x] = s[255];
}

// requires ceil(N/256) <= 256 (N=50000 -> 196 blocks, OK)
__global__ __launch_bounds__(256) void k_scan2(int* __restrict__ bsums, int nb) {
  __shared__ int s[256];
  int t = threadIdx.x;
  int v = (t < nb) ? bsums[t] : 0;
  s[t] = v;
  __syncthreads();
  for (int o = 1; o < 256; o <<= 1) {
    int add = (t >= o) ? s[t - o] : 0;
    __syncthreads();
    s[t] += add;
    __syncthreads();
  }
  if (t < nb) bsums[t] = s[t] - v;
}

// finalize rowptr; init per-XCD cursor bases:
// cursor8[x][v] = rowptr[v] + sum_{y<x} ideg_y[v]
__global__ __launch_bounds__(256) void k_scan3(int* __restrict__ part,
                                               int* __restrict__ cursor8,
                                               const int* __restrict__ bsums,
                                               const unsigned* __restrict__ cnt,
                                               int N, int E) {
  int t = threadIdx.x, g = blockIdx.x * 256 + t;
  if (g < N) {
    int v = part[g] + bsums[blockIdx.x];
    part[g] = v;
    int run = v;
#pragma unroll
    for (int x = 0; x < 8; ++x) {
      cursor8[(size_t)x * N + g] = run;
      run += cnt[(size_t)x * 2u * (unsigned)N + N + g];
    }
  }
  if (g == 0) part[N] = E;
}

// CSR fill with per-XCD cursor copies (WG-scope atomics stay in local L2;
// disjoint per-XCD ranges guarantee globally-unique positions).
__global__ __launch_bounds__(256) void k_fill8(const int* __restrict__ src,
                                               const int* __restrict__ dst,
                                               int* __restrict__ cursor8,
                                               int* __restrict__ colidx,
                                               int N, int E) {
  unsigned xcc;
  asm("s_getreg_b32 %0, hwreg(HW_REG_XCC_ID)" : "=s"(xcc));
  int* my = cursor8 + (size_t)(xcc & 7) * N;
  int e = blockIdx.x * 256 + threadIdx.x;
  if (e < E) {
    int s = src[e];
    int p = __hip_atomic_fetch_add(&my[dst[e]], 1, __ATOMIC_RELAXED,
                                   __HIP_MEMORY_SCOPE_WORKGROUP);
    colidx[p] = s;
  }
}

// W [K][NCOL] fp32 -> WtH/WtL [NCOL][K] bf16 (transposed + hi/lo split). K=256.
__global__ __launch_bounds__(256) void k_wsplit(const float* __restrict__ W,
                                                short* __restrict__ WtH,
                                                short* __restrict__ WtL,
                                                int NCOL) {
  const int K = 256;
  int idx = blockIdx.x * 256 + threadIdx.x;
  if (idx >= K * NCOL) return;
  int k = idx & (K - 1);
  int n = idx >> 8;
  float v = W[(size_t)k * NCOL + n];
  unsigned short h = f2bf(v);
  unsigned short l = f2bf(v - bf2f(h));
  WtH[(size_t)n * K + k] = (short)h;
  WtL[(size_t)n * K + k] = (short)l;
}

// out[m,:] = fp16((A[m,:] @ W) * norm[m]); A (fp32 or fp16) [M][256].
// BM=64 rows/block, full NCOL width. bf16 hi/lo split -> 3 MFMA per tile.
// fp16 A: bf16 hi/lo split is EXACT (11-bit mantissa <= 8+8).
template <int NCOL, typename AT>
__global__ __launch_bounds__(256) void k_gemm_mfma(
    const AT* __restrict__ A, const short* __restrict__ WtH,
    const short* __restrict__ WtL, const float* __restrict__ norm,
    _Float16* __restrict__ out, int M) {
  constexpr int K = 256, BM = 64, BK = 32, PAD = 40, NF = NCOL / 16;
  __shared__ short AH[BM][PAD], AL[BM][PAD];
  __shared__ short BH[NCOL][PAD], BL[NCOL][PAD];
  int tid = threadIdx.x;
  int w = tid >> 6, l = tid & 63;
  int lg = l >> 4, ln = l & 15;
  int row0 = blockIdx.x * BM;

  float4v acc[NF];
#pragma unroll
  for (int i = 0; i < NF; ++i) acc[i] = (float4v){0.f, 0.f, 0.f, 0.f};

  int ar = tid >> 2;        // A-stage row 0..63
  int akq = (tid & 3) * 8;  // A-stage k offset 0/8/16/24

  for (int k0 = 0; k0 < K; k0 += BK) {
    // ---- stage A tile: -> bf16 hi/lo ----
    float av[8];
    int grow = row0 + ar;
    if (grow < M) {
      if constexpr (sizeof(AT) == 4) {
        const float4* ap =
            reinterpret_cast<const float4*>(&A[(size_t)grow * K + k0 + akq]);
        float4 v0 = ap[0], v1 = ap[1];
        av[0] = v0.x; av[1] = v0.y; av[2] = v0.z; av[3] = v0.w;
        av[4] = v1.x; av[5] = v1.y; av[6] = v1.z; av[7] = v1.w;
      } else {
        half8v v =
            *reinterpret_cast<const half8v*>(&A[(size_t)grow * K + k0 + akq]);
#pragma unroll
        for (int i = 0; i < 8; ++i) av[i] = (float)v[i];
      }
    } else {
#pragma unroll
      for (int i = 0; i < 8; ++i) av[i] = 0.f;
    }
    short hh[8], ll[8];
#pragma unroll
    for (int i = 0; i < 8; ++i) {
      unsigned short h = f2bf(av[i]);
      hh[i] = (short)h;
      ll[i] = (short)f2bf(av[i] - bf2f(h));
    }
    *reinterpret_cast<short8v*>(&AH[ar][akq]) = *reinterpret_cast<short8v*>(hh);
    *reinterpret_cast<short8v*>(&AL[ar][akq]) = *reinterpret_cast<short8v*>(ll);

    // ---- stage B tile: NCOL rows x 32 k, bf16 pre-split, 16B chunks ----
#pragma unroll
    for (int c = 0; c < NCOL / 64; ++c) {
      int chunk = c * 256 + tid;
      int bn = chunk >> 2, q = (chunk & 3) * 8;
      *reinterpret_cast<short8v*>(&BH[bn][q]) =
          *reinterpret_cast<const short8v*>(&WtH[(size_t)bn * K + k0 + q]);
      *reinterpret_cast<short8v*>(&BL[bn][q]) =
          *reinterpret_cast<const short8v*>(&WtL[(size_t)bn * K + k0 + q]);
    }
    __syncthreads();

    // ---- MFMA ----
    short8v aH = *reinterpret_cast<short8v*>(&AH[w * 16 + ln][lg * 8]);
    short8v aL = *reinterpret_cast<short8v*>(&AL[w * 16 + ln][lg * 8]);
#pragma unroll
    for (int nf = 0; nf < NF; ++nf) {
      short8v bHv = *reinterpret_cast<short8v*>(&BH[nf * 16 + ln][lg * 8]);
      short8v bLv = *reinterpret_cast<short8v*>(&BL[nf * 16 + ln][lg * 8]);
      acc[nf] = __builtin_amdgcn_mfma_f32_16x16x32_bf16(aH, bHv, acc[nf], 0, 0, 0);
      acc[nf] = __builtin_amdgcn_mfma_f32_16x16x32_bf16(aH, bLv, acc[nf], 0, 0, 0);
      acc[nf] = __builtin_amdgcn_mfma_f32_16x16x32_bf16(aL, bHv, acc[nf], 0, 0, 0);
    }
    __syncthreads();
  }

  // ---- epilogue: scale by norm[row], store fp16 ----
  int rbase = row0 + w * 16 + lg * 4;
  float nrm[4];
#pragma unroll
  for (int j = 0; j < 4; ++j)
    nrm[j] = (rbase + j < M) ? norm[rbase + j] : 0.f;
#pragma unroll
  for (int nf = 0; nf < NF; ++nf) {
#pragma unroll
    for (int j = 0; j < 4; ++j) {
      int r = rbase + j;
      if (r < M)
        out[(size_t)r * NCOL + nf * 16 + ln] = (_Float16)(acc[nf][j] * nrm[j]);
    }
  }
}

// pull aggregation, C=256: one wave/node, lane owns 4 ch; fp16 gather,
// fp32 acc, fp16 store (OT = _Float16) or fp32 store (OT = float).
template <typename OT>
__global__ __launch_bounds__(256) void k_agg256(
    const _Float16* __restrict__ h, const int* __restrict__ rowptr,
    const int* __restrict__ colidx, const float* __restrict__ nd,
    const float* __restrict__ bias, OT* __restrict__ out, int N) {
  int node = blockIdx.x * 4 + (threadIdx.x >> 6);
  int lane = threadIdx.x & 63;
  if (node >= N) return;
  const half4v* hv = reinterpret_cast<const half4v*>(h);
  half4v hs = hv[(size_t)node * 64 + lane]; // self-loop
  float4 acc;
  acc.x = (float)hs[0]; acc.y = (float)hs[1];
  acc.z = (float)hs[2]; acc.w = (float)hs[3];
  int e0 = rowptr[node], e1 = rowptr[node + 1];
  int e = e0;
  for (; e + 7 < e1; e += 8) {
    int si[8];
#pragma unroll
    for (int i = 0; i < 8; ++i) si[i] = colidx[e + i];
    half4v v[8];
#pragma unroll
    for (int i = 0; i < 8; ++i) v[i] = hv[(size_t)si[i] * 64 + lane];
#pragma unroll
    for (int i = 0; i < 8; ++i) {
      acc.x += (float)v[i][0]; acc.y += (float)v[i][1];
      acc.z += (float)v[i][2]; acc.w += (float)v[i][3];
    }
  }
  for (; e < e1; ++e) {
    half4v v0 = hv[(size_t)colidx[e] * 64 + lane];
    acc.x += (float)v0[0]; acc.y += (float)v0[1];
    acc.z += (float)v0[2]; acc.w += (float)v0[3];
  }
  float n = nd[node];
  float4 b = reinterpret_cast<const float4*>(bias)[lane];
  float r0 = fmaxf(fmaf(acc.x, n, b.x), 0.f);
  float r1 = fmaxf(fmaf(acc.y, n, b.y), 0.f);
  float r2 = fmaxf(fmaf(acc.z, n, b.z), 0.f);
  float r3 = fmaxf(fmaf(acc.w, n, b.w), 0.f);
  if constexpr (sizeof(OT) == 2) {
    half4v r = {(_Float16)r0, (_Float16)r1, (_Float16)r2, (_Float16)r3};
    reinterpret_cast<half4v*>(out)[(size_t)node * 64 + lane] = r;
  } else {
    float4 r = make_float4(r0, r1, r2, r3);
    reinterpret_cast<float4*>(out)[(size_t)node * 64 + lane] = r;
  }
}

// pull aggregation, C=128: one wave/node, lane owns 2 ch; fp32 out (d_out)
__global__ __launch_bounds__(256) void k_agg128(
    const _Float16* __restrict__ h, const int* __restrict__ rowptr,
    const int* __restrict__ colidx, const float* __restrict__ nd,
    const float* __restrict__ bias, float* __restrict__ out, int N) {
  int node = blockIdx.x * 4 + (threadIdx.x >> 6);
  int lane = threadIdx.x & 63;
  if (node >= N) return;
  const half2v* hv = reinterpret_cast<const half2v*>(h);
  half2v hs = hv[(size_t)node * 64 + lane]; // self-loop
  float2 acc;
  acc.x = (float)hs[0]; acc.y = (float)hs[1];
  int e0 = rowptr[node], e1 = rowptr[node + 1];
  int e = e0;
  for (; e + 7 < e1; e += 8) {
    int si[8];
#pragma unroll
    for (int i = 0; i < 8; ++i) si[i] = colidx[e + i];
    half2v v[8];
#pragma unroll
    for (int i = 0; i < 8; ++i) v[i] = hv[(size_t)si[i] * 64 + lane];
#pragma unroll
    for (int i = 0; i < 8; ++i) {
      acc.x += (float)v[i][0]; acc.y += (float)v[i][1];
    }
  }
  for (; e < e1; ++e) {
    half2v v0 = hv[(size_t)colidx[e] * 64 + lane];
    acc.x += (float)v0[0]; acc.y += (float)v0[1];
  }
  float n = nd[node];
  float2 b = reinterpret_cast<const float2*>(bias)[lane];
  float2 r;
  r.x = fmaxf(fmaf(acc.x, n, b.x), 0.f);
  r.y = fmaxf(fmaf(acc.y, n, b.y), 0.f);
  reinterpret_cast<float2*>(out)[(size_t)node * 64 + lane] = r;
}

extern "C" void kernel_launch(void* const* d_in, const int* in_sizes, int n_in,
                              void* d_out, int out_size, void* d_ws, size_t ws_size,
                              hipStream_t stream) {
  const float* feats = (const float*)d_in[0];
  const int* src = (const int*)d_in[1];
  const int* dst = (const int*)d_in[2];
  const float* W0 = (const float*)d_in[3];
  const float* b0 = (const float*)d_in[4];
  const float* W1 = (const float*)d_in[5];
  const float* b1 = (const float*)d_in[6];
  float* out = (float*)d_out;

  const int IN_CH = 256, HID = 256, OUT_CH = 128;
  int N = in_sizes[0] / IN_CH;
  int E = in_sizes[1];

  char* ws = (char*)d_ws;
  size_t off = 0;
  auto alloc = [&](size_t bytes) -> void* {
    void* p = ws + off;
    off += (bytes + 255) & ~(size_t)255;
    return p;
  };
  _Float16* h0 = (_Float16*)alloc((size_t)N * HID * 2); // layer-0 GEMM out
  _Float16* x1 = (_Float16*)alloc((size_t)N * HID * 2); // layer-0 agg out, fp16
  float* nsrc   = (float*)alloc((size_t)N * 4);
  float* ndst   = (float*)alloc((size_t)N * 4);
  unsigned* cnt = (unsigned*)alloc((size_t)8 * 2 * N * 4); // 8 per-XCD copies
  int*   rowptr = (int*)alloc((size_t)(N + 1) * 4);
  int*  cursor8 = (int*)alloc((size_t)8 * N * 4);          // 8 per-XCD cursors
  int*   colidx = (int*)alloc((size_t)E * 4);
  int*   bsums  = (int*)alloc(1024);
  short* w0h    = (short*)alloc((size_t)HID * IN_CH * 2);
  short* w0l    = (short*)alloc((size_t)HID * IN_CH * 2);
  short* w1h    = (short*)alloc((size_t)OUT_CH * HID * 2);
  short* w1l    = (short*)alloc((size_t)OUT_CH * HID * 2);
  _Float16* h1  = h0; // reuse: h0 dead after layer-0 agg

  hipMemsetAsync(cnt, 0, (size_t)8 * 2 * N * 4, stream);

  int nbE = (E + 255) / 256, nbN = (N + 255) / 256;
  k_hist8<<<nbE, 256, 0, stream>>>(src, dst, cnt, N, E);
  k_scan1_norm<<<nbN, 256, 0, stream>>>(cnt, rowptr, bsums, nsrc, ndst, N);
  k_scan2<<<1, 256, 0, stream>>>(bsums, nbN);
  k_scan3<<<nbN, 256, 0, stream>>>(rowptr, cursor8, bsums, cnt, N, E);
  k_fill8<<<nbE, 256, 0, stream>>>(src, dst, cursor8, colidx, N, E);

  // weight transpose + bf16 split (K=256 for both layers)
  k_wsplit<<<(IN_CH * HID) / 256, 256, 0, stream>>>(W0, w0h, w0l, HID);
  k_wsplit<<<(HID * OUT_CH) / 256, 256, 0, stream>>>(W1, w1h, w1l, OUT_CH);

  int gm = (N + 63) / 64;
  k_gemm_mfma<256, float><<<gm, 256, 0, stream>>>(feats, w0h, w0l, nsrc, h0, N);
  k_agg256<_Float16><<<(N + 3) / 4, 256, 0, stream>>>(h0, rowptr, colidx, ndst,
                                                      b0, x1, N);

  k_gemm_mfma<128, _Float16><<<gm, 256, 0, stream>>>(x1, w1h, w1l, nsrc, h1, N);
  k_agg128<<<(N + 3) / 4, 256, 0, stream>>>(h1, rowptr, colidx, ndst, b1, out, N);
}

// Round 13
// 382.388 us; speedup vs baseline: 1.1674x; 1.0334x over previous
//
#include <hip/hip_runtime.h>

// ---------------------------------------------------------------------------
// GraphConv x2 (DGL norm='both', self-loops), r13 (= r11/r12, broker dropped
// both before execution; resubmitted unchanged after third desk audit).
// r11+: (a) 4-edge ILP in hist8/fill8 (atomics issued in batches of 8/4 to
//      hide memory-side atomic latency; scope learned irrelevant in r10),
//      (b) scan2 folded into scan3 (each block re-scans 196 block sums),
//      (c) both wsplits in one launch. 10 dispatches total.
// Pipeline: degrees -> norms+scan -> CSR(dst) ->
//           [MFMA-split GEMM+scale -> wave-per-node pull-agg (fp16)] x2
// GEMM: fp32/fp16 A as bf16 hi/lo split, 3x mfma_f32_16x16x32_bf16.
// ---------------------------------------------------------------------------

typedef __attribute__((ext_vector_type(8))) short short8v;
typedef __attribute__((ext_vector_type(4))) float float4v;
typedef __attribute__((ext_vector_type(8))) _Float16 half8v;
typedef __attribute__((ext_vector_type(4))) _Float16 half4v;
typedef __attribute__((ext_vector_type(2))) _Float16 half2v;

__device__ inline unsigned short f2bf(float x) {
  unsigned u = __float_as_uint(x);
  return (unsigned short)((u + 0x7FFFu + ((u >> 16) & 1u)) >> 16);
}
__device__ inline float bf2f(unsigned short b) {
  return __uint_as_float(((unsigned)b) << 16);
}

// per-XCD degree histograms: cnt[x][0..N) = odeg, cnt[x][N..2N) = ideg.
// 4 edges/thread: all 8 atomics issued back-to-back (latency hiding).
__global__ __launch_bounds__(256) void k_hist8(const int* __restrict__ src,
                                               const int* __restrict__ dst,
                                               unsigned* __restrict__ cnt,
                                               int N, int E) {
  unsigned xcc;
  asm("s_getreg_b32 %0, hwreg(HW_REG_XCC_ID)" : "=s"(xcc));
  unsigned* my = cnt + (size_t)(xcc & 7) * 2u * (unsigned)N;
  int base = blockIdx.x * 1024 + threadIdx.x;
  int s4[4], d4[4];
  bool ok[4];
#pragma unroll
  for (int i = 0; i < 4; ++i) {
    int e = base + i * 256;
    ok[i] = e < E;
    if (ok[i]) { s4[i] = src[e]; d4[i] = dst[e]; }
  }
#pragma unroll
  for (int i = 0; i < 4; ++i) {
    if (ok[i]) {
      __hip_atomic_fetch_add(&my[s4[i]], 1u, __ATOMIC_RELAXED,
                             __HIP_MEMORY_SCOPE_WORKGROUP);
      __hip_atomic_fetch_add(&my[N + d4[i]], 1u, __ATOMIC_RELAXED,
                             __HIP_MEMORY_SCOPE_WORKGROUP);
    }
  }
}

// sum 8 copies -> degrees; per-block exclusive scan of in-degree; emit norms.
// bsums[b] = raw block total (scan across blocks happens in k_scan23).
__global__ __launch_bounds__(256) void k_scan1_norm(
    const unsigned* __restrict__ cnt, int* __restrict__ part,
    int* __restrict__ bsums, float* __restrict__ nsrc,
    float* __restrict__ ndst, int N) {
  __shared__ int s[256];
  int t = threadIdx.x, g = blockIdx.x * 256 + t;
  int od = 0, id = 0;
  if (g < N) {
#pragma unroll
    for (int x = 0; x < 8; ++x) {
      od += cnt[(size_t)x * 2u * (unsigned)N + g];
      id += cnt[(size_t)x * 2u * (unsigned)N + N + g];
    }
    nsrc[g] = rsqrtf((float)(od + 1)); // +1 self-loop, deg>=1
    ndst[g] = rsqrtf((float)(id + 1));
  }
  int v = (g < N) ? id : 0;
  s[t] = v;
  __syncthreads();
  for (int o = 1; o < 256; o <<= 1) {
    int add = (t >= o) ? s[t - o] : 0;
    __syncthreads();
    s[t] += add;
    __syncthreads();
  }
  if (g < N) part[g] = s[t] - v;            // exclusive within block
  if (t == 255) bsums[blockIdx.x] = s[255]; // raw block total
}

// finalize rowptr (part) and init per-XCD cursor bases. Each block redundantly
// scans the nb (<=256) raw block sums in LDS (replaces separate scan2 kernel).
// cursor8[x][v] = rowptr[v] + sum_{y<x} ideg_y[v]
__global__ __launch_bounds__(256) void k_scan23(
    int* __restrict__ part, int* __restrict__ cursor8,
    const int* __restrict__ bsums, const unsigned* __restrict__ cnt,
    int nb, int N, int E) {
  __shared__ int s[256];
  int t = threadIdx.x, g = blockIdx.x * 256 + t;
  int v = (t < nb) ? bsums[t] : 0;
  s[t] = v;
  __syncthreads();
  for (int o = 1; o < 256; o <<= 1) {
    int add = (t >= o) ? s[t - o] : 0;
    __syncthreads();
    s[t] += add;
    __syncthreads();
  }
  int off = s[blockIdx.x] - bsums[blockIdx.x]; // exclusive offset of this block
  if (g < N) {
    int r = part[g] + off;
    part[g] = r;
    int run = r;
#pragma unroll
    for (int x = 0; x < 8; ++x) {
      cursor8[(size_t)x * N + g] = run;
      run += cnt[(size_t)x * 2u * (unsigned)N + N + g];
    }
  }
  if (g == 0) part[N] = E;
}

// CSR fill, per-XCD cursors, 4 edges/thread: 4 independent returned atomics
// in flight before the dependent stores (latency hiding).
__global__ __launch_bounds__(256) void k_fill8(const int* __restrict__ src,
                                               const int* __restrict__ dst,
                                               int* __restrict__ cursor8,
                                               int* __restrict__ colidx,
                                               int N, int E) {
  unsigned xcc;
  asm("s_getreg_b32 %0, hwreg(HW_REG_XCC_ID)" : "=s"(xcc));
  int* my = cursor8 + (size_t)(xcc & 7) * N;
  int base = blockIdx.x * 1024 + threadIdx.x;
  int s4[4], d4[4];
  bool ok[4];
#pragma unroll
  for (int i = 0; i < 4; ++i) {
    int e = base + i * 256;
    ok[i] = e < E;
    if (ok[i]) { s4[i] = src[e]; d4[i] = dst[e]; }
  }
  int p4[4];
#pragma unroll
  for (int i = 0; i < 4; ++i) {
    if (ok[i])
      p4[i] = __hip_atomic_fetch_add(&my[d4[i]], 1, __ATOMIC_RELAXED,
                                     __HIP_MEMORY_SCOPE_WORKGROUP);
  }
#pragma unroll
  for (int i = 0; i < 4; ++i) {
    if (ok[i]) colidx[p4[i]] = s4[i];
  }
}

// Both weight matrices -> transposed bf16 hi/lo splits in ONE launch. K=256.
// W0 [256][256] -> w0h/w0l [256][256]; W1 [256][128] -> w1h/w1l [128][256].
__global__ __launch_bounds__(256) void k_wsplit2(
    const float* __restrict__ W0, short* __restrict__ W0tH,
    short* __restrict__ W0tL, const float* __restrict__ W1,
    short* __restrict__ W1tH, short* __restrict__ W1tL) {
  const int K = 256, N0 = 256, N1 = 128;
  int idx = blockIdx.x * 256 + threadIdx.x;
  if (idx < K * N0) {
    int k = idx & (K - 1), n = idx >> 8;
    float v = W0[(size_t)k * N0 + n];
    unsigned short h = f2bf(v);
    W0tH[(size_t)n * K + k] = (short)h;
    W0tL[(size_t)n * K + k] = (short)f2bf(v - bf2f(h));
  } else {
    int j = idx - K * N0;
    if (j < K * N1) {
      int k = j & (K - 1), n = j >> 8;
      float v = W1[(size_t)k * N1 + n];
      unsigned short h = f2bf(v);
      W1tH[(size_t)n * K + k] = (short)h;
      W1tL[(size_t)n * K + k] = (short)f2bf(v - bf2f(h));
    }
  }
}

// out[m,:] = fp16((A[m,:] @ W) * norm[m]); A (fp32 or fp16) [M][256].
// BM=64 rows/block, full NCOL width. bf16 hi/lo split -> 3 MFMA per tile.
// fp16 A: bf16 hi/lo split is EXACT (11-bit mantissa <= 8+8).
template <int NCOL, typename AT>
__global__ __launch_bounds__(256) void k_gemm_mfma(
    const AT* __restrict__ A, const short* __restrict__ WtH,
    const short* __restrict__ WtL, const float* __restrict__ norm,
    _Float16* __restrict__ out, int M) {
  constexpr int K = 256, BM = 64, BK = 32, PAD = 40, NF = NCOL / 16;
  __shared__ short AH[BM][PAD], AL[BM][PAD];
  __shared__ short BH[NCOL][PAD], BL[NCOL][PAD];
  int tid = threadIdx.x;
  int w = tid >> 6, l = tid & 63;
  int lg = l >> 4, ln = l & 15;
  int row0 = blockIdx.x * BM;

  float4v acc[NF];
#pragma unroll
  for (int i = 0; i < NF; ++i) acc[i] = (float4v){0.f, 0.f, 0.f, 0.f};

  int ar = tid >> 2;        // A-stage row 0..63
  int akq = (tid & 3) * 8;  // A-stage k offset 0/8/16/24

  for (int k0 = 0; k0 < K; k0 += BK) {
    // ---- stage A tile: -> bf16 hi/lo ----
    float av[8];
    int grow = row0 + ar;
    if (grow < M) {
      if constexpr (sizeof(AT) == 4) {
        const float4* ap =
            reinterpret_cast<const float4*>(&A[(size_t)grow * K + k0 + akq]);
        float4 v0 = ap[0], v1 = ap[1];
        av[0] = v0.x; av[1] = v0.y; av[2] = v0.z; av[3] = v0.w;
        av[4] = v1.x; av[5] = v1.y; av[6] = v1.z; av[7] = v1.w;
      } else {
        half8v v =
            *reinterpret_cast<const half8v*>(&A[(size_t)grow * K + k0 + akq]);
#pragma unroll
        for (int i = 0; i < 8; ++i) av[i] = (float)v[i];
      }
    } else {
#pragma unroll
      for (int i = 0; i < 8; ++i) av[i] = 0.f;
    }
    short hh[8], ll[8];
#pragma unroll
    for (int i = 0; i < 8; ++i) {
      unsigned short h = f2bf(av[i]);
      hh[i] = (short)h;
      ll[i] = (short)f2bf(av[i] - bf2f(h));
    }
    *reinterpret_cast<short8v*>(&AH[ar][akq]) = *reinterpret_cast<short8v*>(hh);
    *reinterpret_cast<short8v*>(&AL[ar][akq]) = *reinterpret_cast<short8v*>(ll);

    // ---- stage B tile: NCOL rows x 32 k, bf16 pre-split, 16B chunks ----
#pragma unroll
    for (int c = 0; c < NCOL / 64; ++c) {
      int chunk = c * 256 + tid;
      int bn = chunk >> 2, q = (chunk & 3) * 8;
      *reinterpret_cast<short8v*>(&BH[bn][q]) =
          *reinterpret_cast<const short8v*>(&WtH[(size_t)bn * K + k0 + q]);
      *reinterpret_cast<short8v*>(&BL[bn][q]) =
          *reinterpret_cast<const short8v*>(&WtL[(size_t)bn * K + k0 + q]);
    }
    __syncthreads();

    // ---- MFMA ----
    short8v aH = *reinterpret_cast<short8v*>(&AH[w * 16 + ln][lg * 8]);
    short8v aL = *reinterpret_cast<short8v*>(&AL[w * 16 + ln][lg * 8]);
#pragma unroll
    for (int nf = 0; nf < NF; ++nf) {
      short8v bHv = *reinterpret_cast<short8v*>(&BH[nf * 16 + ln][lg * 8]);
      short8v bLv = *reinterpret_cast<short8v*>(&BL[nf * 16 + ln][lg * 8]);
      acc[nf] = __builtin_amdgcn_mfma_f32_16x16x32_bf16(aH, bHv, acc[nf], 0, 0, 0);
      acc[nf] = __builtin_amdgcn_mfma_f32_16x16x32_bf16(aH, bLv, acc[nf], 0, 0, 0);
      acc[nf] = __builtin_amdgcn_mfma_f32_16x16x32_bf16(aL, bHv, acc[nf], 0, 0, 0);
    }
    __syncthreads();
  }

  // ---- epilogue: scale by norm[row], store fp16 ----
  int rbase = row0 + w * 16 + lg * 4;
  float nrm[4];
#pragma unroll
  for (int j = 0; j < 4; ++j)
    nrm[j] = (rbase + j < M) ? norm[rbase + j] : 0.f;
#pragma unroll
  for (int nf = 0; nf < NF; ++nf) {
#pragma unroll
    for (int j = 0; j < 4; ++j) {
      int r = rbase + j;
      if (r < M)
        out[(size_t)r * NCOL + nf * 16 + ln] = (_Float16)(acc[nf][j] * nrm[j]);
    }
  }
}

// pull aggregation, C=256: one wave/node, lane owns 4 ch; fp16 gather,
// fp32 acc, fp16 store.
__global__ __launch_bounds__(256) void k_agg256(
    const _Float16* __restrict__ h, const int* __restrict__ rowptr,
    const int* __restrict__ colidx, const float* __restrict__ nd,
    const float* __restrict__ bias, _Float16* __restrict__ out, int N) {
  int node = blockIdx.x * 4 + (threadIdx.x >> 6);
  int lane = threadIdx.x & 63;
  if (node >= N) return;
  const half4v* hv = reinterpret_cast<const half4v*>(h);
  half4v hs = hv[(size_t)node * 64 + lane]; // self-loop
  float4 acc;
  acc.x = (float)hs[0]; acc.y = (float)hs[1];
  acc.z = (float)hs[2]; acc.w = (float)hs[3];
  int e0 = rowptr[node], e1 = rowptr[node + 1];
  int e = e0;
  for (; e + 7 < e1; e += 8) {
    int si[8];
#pragma unroll
    for (int i = 0; i < 8; ++i) si[i] = colidx[e + i];
    half4v v[8];
#pragma unroll
    for (int i = 0; i < 8; ++i) v[i] = hv[(size_t)si[i] * 64 + lane];
#pragma unroll
    for (int i = 0; i < 8; ++i) {
      acc.x += (float)v[i][0]; acc.y += (float)v[i][1];
      acc.z += (float)v[i][2]; acc.w += (float)v[i][3];
    }
  }
  for (; e < e1; ++e) {
    half4v v0 = hv[(size_t)colidx[e] * 64 + lane];
    acc.x += (float)v0[0]; acc.y += (float)v0[1];
    acc.z += (float)v0[2]; acc.w += (float)v0[3];
  }
  float n = nd[node];
  float4 b = reinterpret_cast<const float4*>(bias)[lane];
  half4v r = {(_Float16)fmaxf(fmaf(acc.x, n, b.x), 0.f),
              (_Float16)fmaxf(fmaf(acc.y, n, b.y), 0.f),
              (_Float16)fmaxf(fmaf(acc.z, n, b.z), 0.f),
              (_Float16)fmaxf(fmaf(acc.w, n, b.w), 0.f)};
  reinterpret_cast<half4v*>(out)[(size_t)node * 64 + lane] = r;
}

// pull aggregation, C=128: one wave/node, lane owns 2 ch; fp32 out (d_out)
__global__ __launch_bounds__(256) void k_agg128(
    const _Float16* __restrict__ h, const int* __restrict__ rowptr,
    const int* __restrict__ colidx, const float* __restrict__ nd,
    const float* __restrict__ bias, float* __restrict__ out, int N) {
  int node = blockIdx.x * 4 + (threadIdx.x >> 6);
  int lane = threadIdx.x & 63;
  if (node >= N) return;
  const half2v* hv = reinterpret_cast<const half2v*>(h);
  half2v hs = hv[(size_t)node * 64 + lane]; // self-loop
  float2 acc;
  acc.x = (float)hs[0]; acc.y = (float)hs[1];
  int e0 = rowptr[node], e1 = rowptr[node + 1];
  int e = e0;
  for (; e + 7 < e1; e += 8) {
    int si[8];
#pragma unroll
    for (int i = 0; i < 8; ++i) si[i] = colidx[e + i];
    half2v v[8];
#pragma unroll
    for (int i = 0; i < 8; ++i) v[i] = hv[(size_t)si[i] * 64 + lane];
#pragma unroll
    for (int i = 0; i < 8; ++i) {
      acc.x += (float)v[i][0]; acc.y += (float)v[i][1];
    }
  }
  for (; e < e1; ++e) {
    half2v v0 = hv[(size_t)colidx[e] * 64 + lane];
    acc.x += (float)v0[0]; acc.y += (float)v0[1];
  }
  float n = nd[node];
  float2 b = reinterpret_cast<const float2*>(bias)[lane];
  float2 r;
  r.x = fmaxf(fmaf(acc.x, n, b.x), 0.f);
  r.y = fmaxf(fmaf(acc.y, n, b.y), 0.f);
  reinterpret_cast<float2*>(out)[(size_t)node * 64 + lane] = r;
}

extern "C" void kernel_launch(void* const* d_in, const int* in_sizes, int n_in,
                              void* d_out, int out_size, void* d_ws, size_t ws_size,
                              hipStream_t stream) {
  const float* feats = (const float*)d_in[0];
  const int* src = (const int*)d_in[1];
  const int* dst = (const int*)d_in[2];
  const float* W0 = (const float*)d_in[3];
  const float* b0 = (const float*)d_in[4];
  const float* W1 = (const float*)d_in[5];
  const float* b1 = (const float*)d_in[6];
  float* out = (float*)d_out;

  const int IN_CH = 256, HID = 256, OUT_CH = 128;
  int N = in_sizes[0] / IN_CH;
  int E = in_sizes[1];

  char* ws = (char*)d_ws;
  size_t off = 0;
  auto alloc = [&](size_t bytes) -> void* {
    void* p = ws + off;
    off += (bytes + 255) & ~(size_t)255;
    return p;
  };
  _Float16* h0 = (_Float16*)alloc((size_t)N * HID * 2); // layer-0 GEMM out
  _Float16* x1 = (_Float16*)alloc((size_t)N * HID * 2); // layer-0 agg out, fp16
  float* nsrc   = (float*)alloc((size_t)N * 4);
  float* ndst   = (float*)alloc((size_t)N * 4);
  unsigned* cnt = (unsigned*)alloc((size_t)8 * 2 * N * 4); // 8 per-XCD copies
  int*   rowptr = (int*)alloc((size_t)(N + 1) * 4);
  int*  cursor8 = (int*)alloc((size_t)8 * N * 4);          // 8 per-XCD cursors
  int*   colidx = (int*)alloc((size_t)E * 4);
  int*   bsums  = (int*)alloc(1024);
  short* w0h    = (short*)alloc((size_t)HID * IN_CH * 2);
  short* w0l    = (short*)alloc((size_t)HID * IN_CH * 2);
  short* w1h    = (short*)alloc((size_t)OUT_CH * HID * 2);
  short* w1l    = (short*)alloc((size_t)OUT_CH * HID * 2);
  _Float16* h1  = h0; // reuse: h0 dead after layer-0 agg

  hipMemsetAsync(cnt, 0, (size_t)8 * 2 * N * 4, stream);

  int nbE4 = (E + 1023) / 1024, nbN = (N + 255) / 256;
  k_hist8<<<nbE4, 256, 0, stream>>>(src, dst, cnt, N, E);
  k_scan1_norm<<<nbN, 256, 0, stream>>>(cnt, rowptr, bsums, nsrc, ndst, N);
  k_scan23<<<nbN, 256, 0, stream>>>(rowptr, cursor8, bsums, cnt, nbN, N, E);
  k_fill8<<<nbE4, 256, 0, stream>>>(src, dst, cursor8, colidx, N, E);

  k_wsplit2<<<(IN_CH * HID + HID * OUT_CH) / 256, 256, 0, stream>>>(
      W0, w0h, w0l, W1, w1h, w1l);

  int gm = (N + 63) / 64;
  k_gemm_mfma<256, float><<<gm, 256, 0, stream>>>(feats, w0h, w0l, nsrc, h0, N);
  k_agg256<<<(N + 3) / 4, 256, 0, stream>>>(h0, rowptr, colidx, ndst, b0, x1, N);

  k_gemm_mfma<128, _Float16><<<gm, 256, 0, stream>>>(x1, w1h, w1l, nsrc, h1, N);
  k_agg128<<<(N + 3) / 4, 256, 0, stream>>>(h1, rowptr, colidx, ndst, b1, out, N);
}

// Round 14
// 376.966 us; speedup vs baseline: 1.1841x; 1.0144x over previous
//
#include <hip/hip_runtime.h>

// ---------------------------------------------------------------------------
// GraphConv x2 (DGL norm='both', self-loops), r14.
// r14 NEW: atomic-free graph prep. r13 showed global atomics rate-bound at
// ~25G/s (hist8 flat under 4-edge ILP). Replace with (slab,chunk) LDS-local
// counting: S=8 node-slabs x NC=32 edge-chunks = 256 blocks.
//   hist: LDS histogram per (slab,chunk) -> coalesced partial flush (no
//         global atomics, no memset needed).
//   fill: position = cursor32[c][dst] + LDS-rank (read-only bases, no
//         global atomics; colidx stores are plain write-back).
// Pipeline: histlds -> scan1(sum 32 partials)+norms -> scan23(rowptr +
//           telescoped per-chunk bases) -> fill_lds ->
//           [MFMA-split GEMM+scale -> wave-per-node pull-agg (fp16)] x2
// GEMM: fp32/fp16 A as bf16 hi/lo split, 3x mfma_f32_16x16x32_bf16.
// ---------------------------------------------------------------------------

typedef __attribute__((ext_vector_type(8))) short short8v;
typedef __attribute__((ext_vector_type(4))) float float4v;
typedef __attribute__((ext_vector_type(8))) _Float16 half8v;
typedef __attribute__((ext_vector_type(4))) _Float16 half4v;
typedef __attribute__((ext_vector_type(2))) _Float16 half2v;

#define NSLAB 8
#define NCHUNK 32
#define MAXW 6272  // max slab width supported (N=50000 -> W=6250)

__device__ inline unsigned short f2bf(float x) {
  unsigned u = __float_as_uint(x);
  return (unsigned short)((u + 0x7FFFu + ((u >> 16) & 1u)) >> 16);
}
__device__ inline float bf2f(unsigned short b) {
  return __uint_as_float(((unsigned)b) << 16);
}

// LDS histogram per (slab, chunk). cntO[c][v], cntI[c][v] partials.
// Full slab-segment flush replaces any global memset.
__global__ __launch_bounds__(256) void k_histlds(
    const int* __restrict__ src, const int* __restrict__ dst,
    unsigned* __restrict__ cntO, unsigned* __restrict__ cntI,
    int W, int CE, int N, int E) {
  __shared__ unsigned ol[MAXW], il[MAXW];
  int s = blockIdx.x & (NSLAB - 1), c = blockIdx.x >> 3;
  int t = threadIdx.x;
  for (int i = t; i < W; i += 256) { ol[i] = 0u; il[i] = 0u; }
  __syncthreads();
  int sW = s * W;
  int e0 = c * CE, e1 = min(e0 + CE, E);
  for (int e = e0 + t; e < e1; e += 256) {
    int sv = src[e], dv = dst[e];
    unsigned so = (unsigned)(sv - sW);
    if (so < (unsigned)W) atomicAdd(&ol[so], 1u);
    unsigned dof = (unsigned)(dv - sW);
    if (dof < (unsigned)W) atomicAdd(&il[dof], 1u);
  }
  __syncthreads();
  int hi = min(W, N - sW); // clip last slab
  for (int i = t; i < hi; i += 256) {
    cntO[(size_t)c * N + sW + i] = ol[i];
    cntI[(size_t)c * N + sW + i] = il[i];
  }
}

// sum 32 partials -> degrees; per-block exclusive scan of in-degree; norms.
// bsums[b] = raw block total.
__global__ __launch_bounds__(256) void k_scan1_norm(
    const unsigned* __restrict__ cntO, const unsigned* __restrict__ cntI,
    int* __restrict__ part, int* __restrict__ bsums,
    float* __restrict__ nsrc, float* __restrict__ ndst, int N) {
  __shared__ int s[256];
  int t = threadIdx.x, g = blockIdx.x * 256 + t;
  int od = 0, id = 0;
  if (g < N) {
#pragma unroll
    for (int c = 0; c < NCHUNK; ++c) {
      od += cntO[(size_t)c * N + g];
      id += cntI[(size_t)c * N + g];
    }
    nsrc[g] = rsqrtf((float)(od + 1)); // +1 self-loop, deg>=1
    ndst[g] = rsqrtf((float)(id + 1));
  }
  int v = (g < N) ? id : 0;
  s[t] = v;
  __syncthreads();
  for (int o = 1; o < 256; o <<= 1) {
    int add = (t >= o) ? s[t - o] : 0;
    __syncthreads();
    s[t] += add;
    __syncthreads();
  }
  if (g < N) part[g] = s[t] - v;            // exclusive within block
  if (t == 255) bsums[blockIdx.x] = s[255]; // raw block total
}

// finalize rowptr; telescope per-chunk bases:
// cursor32[c][v] = rowptr[v] + sum_{c'<c} cntI[c'][v]. (read-only for fill)
// Each block redundantly scans the nb (<=256) raw block sums in LDS.
__global__ __launch_bounds__(256) void k_scan23(
    int* __restrict__ part, int* __restrict__ cursor32,
    const int* __restrict__ bsums, const unsigned* __restrict__ cntI,
    int nb, int N, int E) {
  __shared__ int s[256];
  int t = threadIdx.x, g = blockIdx.x * 256 + t;
  int v = (t < nb) ? bsums[t] : 0;
  s[t] = v;
  __syncthreads();
  for (int o = 1; o < 256; o <<= 1) {
    int add = (t >= o) ? s[t - o] : 0;
    __syncthreads();
    s[t] += add;
    __syncthreads();
  }
  int off = s[blockIdx.x] - bsums[blockIdx.x]; // exclusive offset of this block
  if (g < N) {
    int r = part[g] + off;
    part[g] = r;
    int run = r;
#pragma unroll
    for (int c = 0; c < NCHUNK; ++c) {
      cursor32[(size_t)c * N + g] = run;
      run += cntI[(size_t)c * N + g];
    }
  }
  if (g == 0) part[N] = E;
}

// CSR fill: LDS rank counters + read-only per-chunk bases. No global atomics.
__global__ __launch_bounds__(256) void k_fill_lds(
    const int* __restrict__ src, const int* __restrict__ dst,
    const int* __restrict__ cursor32, int* __restrict__ colidx,
    int W, int CE, int N, int E) {
  __shared__ unsigned rl[MAXW];
  int s = blockIdx.x & (NSLAB - 1), c = blockIdx.x >> 3;
  int t = threadIdx.x;
  for (int i = t; i < W; i += 256) rl[i] = 0u;
  __syncthreads();
  int sW = s * W;
  int e0 = c * CE, e1 = min(e0 + CE, E);
  const int* cbase = cursor32 + (size_t)c * N;
  for (int e = e0 + t; e < e1; e += 256) {
    int sv = src[e], dv = dst[e];
    unsigned dof = (unsigned)(dv - sW);
    if (dof < (unsigned)W) {
      unsigned r = atomicAdd(&rl[dof], 1u);
      colidx[cbase[dv] + (int)r] = sv;
    }
  }
}

// Both weight matrices -> transposed bf16 hi/lo splits in ONE launch. K=256.
__global__ __launch_bounds__(256) void k_wsplit2(
    const float* __restrict__ W0, short* __restrict__ W0tH,
    short* __restrict__ W0tL, const float* __restrict__ W1,
    short* __restrict__ W1tH, short* __restrict__ W1tL) {
  const int K = 256, N0 = 256, N1 = 128;
  int idx = blockIdx.x * 256 + threadIdx.x;
  if (idx < K * N0) {
    int k = idx & (K - 1), n = idx >> 8;
    float v = W0[(size_t)k * N0 + n];
    unsigned short h = f2bf(v);
    W0tH[(size_t)n * K + k] = (short)h;
    W0tL[(size_t)n * K + k] = (short)f2bf(v - bf2f(h));
  } else {
    int j = idx - K * N0;
    if (j < K * N1) {
      int k = j & (K - 1), n = j >> 8;
      float v = W1[(size_t)k * N1 + n];
      unsigned short h = f2bf(v);
      W1tH[(size_t)n * K + k] = (short)h;
      W1tL[(size_t)n * K + k] = (short)f2bf(v - bf2f(h));
    }
  }
}

// out[m,:] = fp16((A[m,:] @ W) * norm[m]); A (fp32 or fp16) [M][256].
// BM=64 rows/block, full NCOL width. bf16 hi/lo split -> 3 MFMA per tile.
template <int NCOL, typename AT>
__global__ __launch_bounds__(256) void k_gemm_mfma(
    const AT* __restrict__ A, const short* __restrict__ WtH,
    const short* __restrict__ WtL, const float* __restrict__ norm,
    _Float16* __restrict__ out, int M) {
  constexpr int K = 256, BM = 64, BK = 32, PAD = 40, NF = NCOL / 16;
  __shared__ short AH[BM][PAD], AL[BM][PAD];
  __shared__ short BH[NCOL][PAD], BL[NCOL][PAD];
  int tid = threadIdx.x;
  int w = tid >> 6, l = tid & 63;
  int lg = l >> 4, ln = l & 15;
  int row0 = blockIdx.x * BM;

  float4v acc[NF];
#pragma unroll
  for (int i = 0; i < NF; ++i) acc[i] = (float4v){0.f, 0.f, 0.f, 0.f};

  int ar = tid >> 2;        // A-stage row 0..63
  int akq = (tid & 3) * 8;  // A-stage k offset 0/8/16/24

  for (int k0 = 0; k0 < K; k0 += BK) {
    // ---- stage A tile: -> bf16 hi/lo ----
    float av[8];
    int grow = row0 + ar;
    if (grow < M) {
      if constexpr (sizeof(AT) == 4) {
        const float4* ap =
            reinterpret_cast<const float4*>(&A[(size_t)grow * K + k0 + akq]);
        float4 v0 = ap[0], v1 = ap[1];
        av[0] = v0.x; av[1] = v0.y; av[2] = v0.z; av[3] = v0.w;
        av[4] = v1.x; av[5] = v1.y; av[6] = v1.z; av[7] = v1.w;
      } else {
        half8v v =
            *reinterpret_cast<const half8v*>(&A[(size_t)grow * K + k0 + akq]);
#pragma unroll
        for (int i = 0; i < 8; ++i) av[i] = (float)v[i];
      }
    } else {
#pragma unroll
      for (int i = 0; i < 8; ++i) av[i] = 0.f;
    }
    short hh[8], ll[8];
#pragma unroll
    for (int i = 0; i < 8; ++i) {
      unsigned short h = f2bf(av[i]);
      hh[i] = (short)h;
      ll[i] = (short)f2bf(av[i] - bf2f(h));
    }
    *reinterpret_cast<short8v*>(&AH[ar][akq]) = *reinterpret_cast<short8v*>(hh);
    *reinterpret_cast<short8v*>(&AL[ar][akq]) = *reinterpret_cast<short8v*>(ll);

    // ---- stage B tile: NCOL rows x 32 k, bf16 pre-split, 16B chunks ----
#pragma unroll
    for (int c = 0; c < NCOL / 64; ++c) {
      int chunk = c * 256 + tid;
      int bn = chunk >> 2, q = (chunk & 3) * 8;
      *reinterpret_cast<short8v*>(&BH[bn][q]) =
          *reinterpret_cast<const short8v*>(&WtH[(size_t)bn * K + k0 + q]);
      *reinterpret_cast<short8v*>(&BL[bn][q]) =
          *reinterpret_cast<const short8v*>(&WtL[(size_t)bn * K + k0 + q]);
    }
    __syncthreads();

    // ---- MFMA ----
    short8v aH = *reinterpret_cast<short8v*>(&AH[w * 16 + ln][lg * 8]);
    short8v aL = *reinterpret_cast<short8v*>(&AL[w * 16 + ln][lg * 8]);
#pragma unroll
    for (int nf = 0; nf < NF; ++nf) {
      short8v bHv = *reinterpret_cast<short8v*>(&BH[nf * 16 + ln][lg * 8]);
      short8v bLv = *reinterpret_cast<short8v*>(&BL[nf * 16 + ln][lg * 8]);
      acc[nf] = __builtin_amdgcn_mfma_f32_16x16x32_bf16(aH, bHv, acc[nf], 0, 0, 0);
      acc[nf] = __builtin_amdgcn_mfma_f32_16x16x32_bf16(aH, bLv, acc[nf], 0, 0, 0);
      acc[nf] = __builtin_amdgcn_mfma_f32_16x16x32_bf16(aL, bHv, acc[nf], 0, 0, 0);
    }
    __syncthreads();
  }

  // ---- epilogue: scale by norm[row], store fp16 ----
  int rbase = row0 + w * 16 + lg * 4;
  float nrm[4];
#pragma unroll
  for (int j = 0; j < 4; ++j)
    nrm[j] = (rbase + j < M) ? norm[rbase + j] : 0.f;
#pragma unroll
  for (int nf = 0; nf < NF; ++nf) {
#pragma unroll
    for (int j = 0; j < 4; ++j) {
      int r = rbase + j;
      if (r < M)
        out[(size_t)r * NCOL + nf * 16 + ln] = (_Float16)(acc[nf][j] * nrm[j]);
    }
  }
}

// pull aggregation, C=256: one wave/node, lane owns 4 ch; fp16 gather,
// fp32 acc, fp16 store.
__global__ __launch_bounds__(256) void k_agg256(
    const _Float16* __restrict__ h, const int* __restrict__ rowptr,
    const int* __restrict__ colidx, const float* __restrict__ nd,
    const float* __restrict__ bias, _Float16* __restrict__ out, int N) {
  int node = blockIdx.x * 4 + (threadIdx.x >> 6);
  int lane = threadIdx.x & 63;
  if (node >= N) return;
  const half4v* hv = reinterpret_cast<const half4v*>(h);
  half4v hs = hv[(size_t)node * 64 + lane]; // self-loop
  float4 acc;
  acc.x = (float)hs[0]; acc.y = (float)hs[1];
  acc.z = (float)hs[2]; acc.w = (float)hs[3];
  int e0 = rowptr[node], e1 = rowptr[node + 1];
  int e = e0;
  for (; e + 7 < e1; e += 8) {
    int si[8];
#pragma unroll
    for (int i = 0; i < 8; ++i) si[i] = colidx[e + i];
    half4v v[8];
#pragma unroll
    for (int i = 0; i < 8; ++i) v[i] = hv[(size_t)si[i] * 64 + lane];
#pragma unroll
    for (int i = 0; i < 8; ++i) {
      acc.x += (float)v[i][0]; acc.y += (float)v[i][1];
      acc.z += (float)v[i][2]; acc.w += (float)v[i][3];
    }
  }
  for (; e < e1; ++e) {
    half4v v0 = hv[(size_t)colidx[e] * 64 + lane];
    acc.x += (float)v0[0]; acc.y += (float)v0[1];
    acc.z += (float)v0[2]; acc.w += (float)v0[3];
  }
  float n = nd[node];
  float4 b = reinterpret_cast<const float4*>(bias)[lane];
  half4v r = {(_Float16)fmaxf(fmaf(acc.x, n, b.x), 0.f),
              (_Float16)fmaxf(fmaf(acc.y, n, b.y), 0.f),
              (_Float16)fmaxf(fmaf(acc.z, n, b.z), 0.f),
              (_Float16)fmaxf(fmaf(acc.w, n, b.w), 0.f)};
  reinterpret_cast<half4v*>(out)[(size_t)node * 64 + lane] = r;
}

// pull aggregation, C=128: one wave/node, lane owns 2 ch; fp32 out (d_out)
__global__ __launch_bounds__(256) void k_agg128(
    const _Float16* __restrict__ h, const int* __restrict__ rowptr,
    const int* __restrict__ colidx, const float* __restrict__ nd,
    const float* __restrict__ bias, float* __restrict__ out, int N) {
  int node = blockIdx.x * 4 + (threadIdx.x >> 6);
  int lane = threadIdx.x & 63;
  if (node >= N) return;
  const half2v* hv = reinterpret_cast<const half2v*>(h);
  half2v hs = hv[(size_t)node * 64 + lane]; // self-loop
  float2 acc;
  acc.x = (float)hs[0]; acc.y = (float)hs[1];
  int e0 = rowptr[node], e1 = rowptr[node + 1];
  int e = e0;
  for (; e + 7 < e1; e += 8) {
    int si[8];
#pragma unroll
    for (int i = 0; i < 8; ++i) si[i] = colidx[e + i];
    half2v v[8];
#pragma unroll
    for (int i = 0; i < 8; ++i) v[i] = hv[(size_t)si[i] * 64 + lane];
#pragma unroll
    for (int i = 0; i < 8; ++i) {
      acc.x += (float)v[i][0]; acc.y += (float)v[i][1];
    }
  }
  for (; e < e1; ++e) {
    half2v v0 = hv[(size_t)colidx[e] * 64 + lane];
    acc.x += (float)v0[0]; acc.y += (float)v0[1];
  }
  float n = nd[node];
  float2 b = reinterpret_cast<const float2*>(bias)[lane];
  float2 r;
  r.x = fmaxf(fmaf(acc.x, n, b.x), 0.f);
  r.y = fmaxf(fmaf(acc.y, n, b.y), 0.f);
  reinterpret_cast<float2*>(out)[(size_t)node * 64 + lane] = r;
}

extern "C" void kernel_launch(void* const* d_in, const int* in_sizes, int n_in,
                              void* d_out, int out_size, void* d_ws, size_t ws_size,
                              hipStream_t stream) {
  const float* feats = (const float*)d_in[0];
  const int* src = (const int*)d_in[1];
  const int* dst = (const int*)d_in[2];
  const float* W0 = (const float*)d_in[3];
  const float* b0 = (const float*)d_in[4];
  const float* W1 = (const float*)d_in[5];
  const float* b1 = (const float*)d_in[6];
  float* out = (float*)d_out;

  const int IN_CH = 256, HID = 256, OUT_CH = 128;
  int N = in_sizes[0] / IN_CH;
  int E = in_sizes[1];
  int W = (N + NSLAB - 1) / NSLAB;    // 6250 (<= MAXW)
  int CE = (E + NCHUNK - 1) / NCHUNK; // 25000

  char* ws = (char*)d_ws;
  size_t off = 0;
  auto alloc = [&](size_t bytes) -> void* {
    void* p = ws + off;
    off += (bytes + 255) & ~(size_t)255;
    return p;
  };
  _Float16* h0 = (_Float16*)alloc((size_t)N * HID * 2); // layer-0 GEMM out
  _Float16* x1 = (_Float16*)alloc((size_t)N * HID * 2); // layer-0 agg out
  float* nsrc   = (float*)alloc((size_t)N * 4);
  float* ndst   = (float*)alloc((size_t)N * 4);
  unsigned* cntO = (unsigned*)alloc((size_t)NCHUNK * N * 4); // per-chunk odeg
  unsigned* cntI = (unsigned*)alloc((size_t)NCHUNK * N * 4); // per-chunk ideg
  int*   rowptr = (int*)alloc((size_t)(N + 1) * 4);
  int* cursor32 = (int*)alloc((size_t)NCHUNK * N * 4); // per-chunk bases (RO)
  int*   colidx = (int*)alloc((size_t)E * 4);
  int*   bsums  = (int*)alloc(1024);
  short* w0h    = (short*)alloc((size_t)HID * IN_CH * 2);
  short* w0l    = (short*)alloc((size_t)HID * IN_CH * 2);
  short* w1h    = (short*)alloc((size_t)OUT_CH * HID * 2);
  short* w1l    = (short*)alloc((size_t)OUT_CH * HID * 2);
  _Float16* h1  = h0; // reuse: h0 dead after layer-0 agg

  int nbN = (N + 255) / 256;
  k_histlds<<<NSLAB * NCHUNK, 256, 0, stream>>>(src, dst, cntO, cntI, W, CE, N, E);
  k_scan1_norm<<<nbN, 256, 0, stream>>>(cntO, cntI, rowptr, bsums, nsrc, ndst, N);
  k_scan23<<<nbN, 256, 0, stream>>>(rowptr, cursor32, bsums, cntI, nbN, N, E);
  k_fill_lds<<<NSLAB * NCHUNK, 256, 0, stream>>>(src, dst, cursor32, colidx, W, CE, N, E);

  k_wsplit2<<<(IN_CH * HID + HID * OUT_CH) / 256, 256, 0, stream>>>(
      W0, w0h, w0l, W1, w1h, w1l);

  int gm = (N + 63) / 64;
  k_gemm_mfma<256, float><<<gm, 256, 0, stream>>>(feats, w0h, w0l, nsrc, h0, N);
  k_agg256<<<(N + 3) / 4, 256, 0, stream>>>(h0, rowptr, colidx, ndst, b0, x1, N);

  k_gemm_mfma<128, _Float16><<<gm, 256, 0, stream>>>(x1, w1h, w1l, nsrc, h1, N);
  k_agg128<<<(N + 3) / 4, 256, 0, stream>>>(h1, rowptr, colidx, ndst, b1, out, N);
}

// Round 15
// 371.167 us; speedup vs baseline: 1.2026x; 1.0156x over previous
//
#include <hip/hip_runtime.h>

// ---------------------------------------------------------------------------
// GraphConv x2 (DGL norm='both', self-loops), r15.
// r15 NEW: GEMM inner loop switched 16x16x32 -> 32x32x16 MFMA, 2x2 wave grid
// (wave = 32 rows x NCOL/2 cols). Per-wave ds_read_b128 per K-step: 34 -> 20
// (B-fragment redundancy halved), MFMA FLOP/cyc 3378 -> 4061 (m119). C/D map
// col=lane&31, row=(reg&3)+8*(reg>>2)+4*(lane>>5) (m74/m101 HW-verified).
// Prep unchanged from r14 (atomic-free LDS hist/fill).
// ---------------------------------------------------------------------------

typedef __attribute__((ext_vector_type(8))) short short8v;
typedef __attribute__((ext_vector_type(16))) float float16v;
typedef __attribute__((ext_vector_type(8))) _Float16 half8v;
typedef __attribute__((ext_vector_type(4))) _Float16 half4v;
typedef __attribute__((ext_vector_type(2))) _Float16 half2v;

#define NSLAB 8
#define NCHUNK 32
#define MAXW 6272  // max slab width supported (N=50000 -> W=6250)

__device__ inline unsigned short f2bf(float x) {
  unsigned u = __float_as_uint(x);
  return (unsigned short)((u + 0x7FFFu + ((u >> 16) & 1u)) >> 16);
}
__device__ inline float bf2f(unsigned short b) {
  return __uint_as_float(((unsigned)b) << 16);
}

// LDS histogram per (slab, chunk). cntO[c][v], cntI[c][v] partials.
__global__ __launch_bounds__(256) void k_histlds(
    const int* __restrict__ src, const int* __restrict__ dst,
    unsigned* __restrict__ cntO, unsigned* __restrict__ cntI,
    int W, int CE, int N, int E) {
  __shared__ unsigned ol[MAXW], il[MAXW];
  int s = blockIdx.x & (NSLAB - 1), c = blockIdx.x >> 3;
  int t = threadIdx.x;
  for (int i = t; i < W; i += 256) { ol[i] = 0u; il[i] = 0u; }
  __syncthreads();
  int sW = s * W;
  int e0 = c * CE, e1 = min(e0 + CE, E);
  for (int e = e0 + t; e < e1; e += 256) {
    int sv = src[e], dv = dst[e];
    unsigned so = (unsigned)(sv - sW);
    if (so < (unsigned)W) atomicAdd(&ol[so], 1u);
    unsigned dof = (unsigned)(dv - sW);
    if (dof < (unsigned)W) atomicAdd(&il[dof], 1u);
  }
  __syncthreads();
  int hi = min(W, N - sW); // clip last slab
  for (int i = t; i < hi; i += 256) {
    cntO[(size_t)c * N + sW + i] = ol[i];
    cntI[(size_t)c * N + sW + i] = il[i];
  }
}

// sum 32 partials -> degrees; per-block exclusive scan of in-degree; norms.
__global__ __launch_bounds__(256) void k_scan1_norm(
    const unsigned* __restrict__ cntO, const unsigned* __restrict__ cntI,
    int* __restrict__ part, int* __restrict__ bsums,
    float* __restrict__ nsrc, float* __restrict__ ndst, int N) {
  __shared__ int s[256];
  int t = threadIdx.x, g = blockIdx.x * 256 + t;
  int od = 0, id = 0;
  if (g < N) {
#pragma unroll
    for (int c = 0; c < NCHUNK; ++c) {
      od += cntO[(size_t)c * N + g];
      id += cntI[(size_t)c * N + g];
    }
    nsrc[g] = rsqrtf((float)(od + 1)); // +1 self-loop, deg>=1
    ndst[g] = rsqrtf((float)(id + 1));
  }
  int v = (g < N) ? id : 0;
  s[t] = v;
  __syncthreads();
  for (int o = 1; o < 256; o <<= 1) {
    int add = (t >= o) ? s[t - o] : 0;
    __syncthreads();
    s[t] += add;
    __syncthreads();
  }
  if (g < N) part[g] = s[t] - v;            // exclusive within block
  if (t == 255) bsums[blockIdx.x] = s[255]; // raw block total
}

// finalize rowptr; telescope per-chunk bases:
// cursor32[c][v] = rowptr[v] + sum_{c'<c} cntI[c'][v].
__global__ __launch_bounds__(256) void k_scan23(
    int* __restrict__ part, int* __restrict__ cursor32,
    const int* __restrict__ bsums, const unsigned* __restrict__ cntI,
    int nb, int N, int E) {
  __shared__ int s[256];
  int t = threadIdx.x, g = blockIdx.x * 256 + t;
  int v = (t < nb) ? bsums[t] : 0;
  s[t] = v;
  __syncthreads();
  for (int o = 1; o < 256; o <<= 1) {
    int add = (t >= o) ? s[t - o] : 0;
    __syncthreads();
    s[t] += add;
    __syncthreads();
  }
  int off = s[blockIdx.x] - bsums[blockIdx.x]; // exclusive offset of this block
  if (g < N) {
    int r = part[g] + off;
    part[g] = r;
    int run = r;
#pragma unroll
    for (int c = 0; c < NCHUNK; ++c) {
      cursor32[(size_t)c * N + g] = run;
      run += cntI[(size_t)c * N + g];
    }
  }
  if (g == 0) part[N] = E;
}

// CSR fill: LDS rank counters + read-only per-chunk bases. No global atomics.
__global__ __launch_bounds__(256) void k_fill_lds(
    const int* __restrict__ src, const int* __restrict__ dst,
    const int* __restrict__ cursor32, int* __restrict__ colidx,
    int W, int CE, int N, int E) {
  __shared__ unsigned rl[MAXW];
  int s = blockIdx.x & (NSLAB - 1), c = blockIdx.x >> 3;
  int t = threadIdx.x;
  for (int i = t; i < W; i += 256) rl[i] = 0u;
  __syncthreads();
  int sW = s * W;
  int e0 = c * CE, e1 = min(e0 + CE, E);
  const int* cbase = cursor32 + (size_t)c * N;
  for (int e = e0 + t; e < e1; e += 256) {
    int sv = src[e], dv = dst[e];
    unsigned dof = (unsigned)(dv - sW);
    if (dof < (unsigned)W) {
      unsigned r = atomicAdd(&rl[dof], 1u);
      colidx[cbase[dv] + (int)r] = sv;
    }
  }
}

// Both weight matrices -> transposed bf16 hi/lo splits in ONE launch. K=256.
__global__ __launch_bounds__(256) void k_wsplit2(
    const float* __restrict__ W0, short* __restrict__ W0tH,
    short* __restrict__ W0tL, const float* __restrict__ W1,
    short* __restrict__ W1tH, short* __restrict__ W1tL) {
  const int K = 256, N0 = 256, N1 = 128;
  int idx = blockIdx.x * 256 + threadIdx.x;
  if (idx < K * N0) {
    int k = idx & (K - 1), n = idx >> 8;
    float v = W0[(size_t)k * N0 + n];
    unsigned short h = f2bf(v);
    W0tH[(size_t)n * K + k] = (short)h;
    W0tL[(size_t)n * K + k] = (short)f2bf(v - bf2f(h));
  } else {
    int j = idx - K * N0;
    if (j < K * N1) {
      int k = j & (K - 1), n = j >> 8;
      float v = W1[(size_t)k * N1 + n];
      unsigned short h = f2bf(v);
      W1tH[(size_t)n * K + k] = (short)h;
      W1tL[(size_t)n * K + k] = (short)f2bf(v - bf2f(h));
    }
  }
}

// out[m,:] = fp16((A[m,:] @ W) * norm[m]); A (fp32 or fp16) [M][256].
// BM=64, 4 waves in 2x2 grid; wave = 32 rows x NCOL/2 cols of 32x32 frags.
// bf16 hi/lo split -> 3 MFMA (hh,hl,lh) per fragment per k-subtile.
// A/B share the same (lane,k) map (within-K permutation cancels).
// C/D: col=lane&31, row=(reg&3)+8*(reg>>2)+4*(lane>>5)  [m74/m101].
template <int NCOL, typename AT>
__global__ __launch_bounds__(256) void k_gemm_mfma(
    const AT* __restrict__ A, const short* __restrict__ WtH,
    const short* __restrict__ WtL, const float* __restrict__ norm,
    _Float16* __restrict__ out, int M) {
  constexpr int K = 256, BM = 64, BK = 32, PAD = 40;
  constexpr int WCOLS = NCOL / 2; // cols per wave
  constexpr int NCF = WCOLS / 32; // 32-col fragments per wave
  __shared__ short AH[BM][PAD], AL[BM][PAD];
  __shared__ short BH[NCOL][PAD], BL[NCOL][PAD];
  int tid = threadIdx.x;
  int wid = tid >> 6, l = tid & 63;
  int wr = wid >> 1, wc = wid & 1;
  int l31 = l & 31, lh = l >> 5;
  int row0 = blockIdx.x * BM;

  float16v acc[NCF];
#pragma unroll
  for (int i = 0; i < NCF; ++i)
#pragma unroll
    for (int j = 0; j < 16; ++j) acc[i][j] = 0.f;

  int ar = tid >> 2;        // A-stage row 0..63
  int akq = (tid & 3) * 8;  // A-stage k offset 0/8/16/24

  for (int k0 = 0; k0 < K; k0 += BK) {
    // ---- stage A tile: -> bf16 hi/lo ----
    float av[8];
    int grow = row0 + ar;
    if (grow < M) {
      if constexpr (sizeof(AT) == 4) {
        const float4* ap =
            reinterpret_cast<const float4*>(&A[(size_t)grow * K + k0 + akq]);
        float4 v0 = ap[0], v1 = ap[1];
        av[0] = v0.x; av[1] = v0.y; av[2] = v0.z; av[3] = v0.w;
        av[4] = v1.x; av[5] = v1.y; av[6] = v1.z; av[7] = v1.w;
      } else {
        half8v v =
            *reinterpret_cast<const half8v*>(&A[(size_t)grow * K + k0 + akq]);
#pragma unroll
        for (int i = 0; i < 8; ++i) av[i] = (float)v[i];
      }
    } else {
#pragma unroll
      for (int i = 0; i < 8; ++i) av[i] = 0.f;
    }
    short hh[8], ll[8];
#pragma unroll
    for (int i = 0; i < 8; ++i) {
      unsigned short h = f2bf(av[i]);
      hh[i] = (short)h;
      ll[i] = (short)f2bf(av[i] - bf2f(h));
    }
    *reinterpret_cast<short8v*>(&AH[ar][akq]) = *reinterpret_cast<short8v*>(hh);
    *reinterpret_cast<short8v*>(&AL[ar][akq]) = *reinterpret_cast<short8v*>(ll);

    // ---- stage B tile: NCOL rows x 32 k, bf16 pre-split, 16B chunks ----
#pragma unroll
    for (int c = 0; c < NCOL / 64; ++c) {
      int chunk = c * 256 + tid;
      int bn = chunk >> 2, q = (chunk & 3) * 8;
      *reinterpret_cast<short8v*>(&BH[bn][q]) =
          *reinterpret_cast<const short8v*>(&WtH[(size_t)bn * K + k0 + q]);
      *reinterpret_cast<short8v*>(&BL[bn][q]) =
          *reinterpret_cast<const short8v*>(&WtL[(size_t)bn * K + k0 + q]);
    }
    __syncthreads();

    // ---- MFMA: 2 k-subtiles of 16, NCF col-fragments, 3 split combos ----
#pragma unroll
    for (int ks = 0; ks < 2; ++ks) {
      short8v aH = *reinterpret_cast<short8v*>(&AH[wr * 32 + l31][ks * 16 + lh * 8]);
      short8v aL = *reinterpret_cast<short8v*>(&AL[wr * 32 + l31][ks * 16 + lh * 8]);
#pragma unroll
      for (int cf = 0; cf < NCF; ++cf) {
        int bi = wc * WCOLS + cf * 32 + l31;
        short8v bH = *reinterpret_cast<short8v*>(&BH[bi][ks * 16 + lh * 8]);
        short8v bL = *reinterpret_cast<short8v*>(&BL[bi][ks * 16 + lh * 8]);
        acc[cf] = __builtin_amdgcn_mfma_f32_32x32x16_bf16(aH, bH, acc[cf], 0, 0, 0);
        acc[cf] = __builtin_amdgcn_mfma_f32_32x32x16_bf16(aH, bL, acc[cf], 0, 0, 0);
        acc[cf] = __builtin_amdgcn_mfma_f32_32x32x16_bf16(aL, bH, acc[cf], 0, 0, 0);
      }
    }
    __syncthreads();
  }

  // ---- epilogue: scale by norm[row], store fp16 ----
  int rbase = row0 + wr * 32 + 4 * lh;
  float nrm[16];
#pragma unroll
  for (int r = 0; r < 16; ++r) {
    int row = rbase + (r & 3) + 8 * (r >> 2);
    nrm[r] = (row < M) ? norm[row] : 0.f;
  }
#pragma unroll
  for (int cf = 0; cf < NCF; ++cf) {
    int col = wc * WCOLS + cf * 32 + l31;
#pragma unroll
    for (int r = 0; r < 16; ++r) {
      int row = rbase + (r & 3) + 8 * (r >> 2);
      if (row < M)
        out[(size_t)row * NCOL + col] = (_Float16)(acc[cf][r] * nrm[r]);
    }
  }
}

// pull aggregation, C=256: one wave/node, lane owns 4 ch; fp16 gather,
// fp32 acc, fp16 store.
__global__ __launch_bounds__(256) void k_agg256(
    const _Float16* __restrict__ h, const int* __restrict__ rowptr,
    const int* __restrict__ colidx, const float* __restrict__ nd,
    const float* __restrict__ bias, _Float16* __restrict__ out, int N) {
  int node = blockIdx.x * 4 + (threadIdx.x >> 6);
  int lane = threadIdx.x & 63;
  if (node >= N) return;
  const half4v* hv = reinterpret_cast<const half4v*>(h);
  half4v hs = hv[(size_t)node * 64 + lane]; // self-loop
  float4 acc;
  acc.x = (float)hs[0]; acc.y = (float)hs[1];
  acc.z = (float)hs[2]; acc.w = (float)hs[3];
  int e0 = rowptr[node], e1 = rowptr[node + 1];
  int e = e0;
  for (; e + 7 < e1; e += 8) {
    int si[8];
#pragma unroll
    for (int i = 0; i < 8; ++i) si[i] = colidx[e + i];
    half4v v[8];
#pragma unroll
    for (int i = 0; i < 8; ++i) v[i] = hv[(size_t)si[i] * 64 + lane];
#pragma unroll
    for (int i = 0; i < 8; ++i) {
      acc.x += (float)v[i][0]; acc.y += (float)v[i][1];
      acc.z += (float)v[i][2]; acc.w += (float)v[i][3];
    }
  }
  for (; e < e1; ++e) {
    half4v v0 = hv[(size_t)colidx[e] * 64 + lane];
    acc.x += (float)v0[0]; acc.y += (float)v0[1];
    acc.z += (float)v0[2]; acc.w += (float)v0[3];
  }
  float n = nd[node];
  float4 b = reinterpret_cast<const float4*>(bias)[lane];
  half4v r = {(_Float16)fmaxf(fmaf(acc.x, n, b.x), 0.f),
              (_Float16)fmaxf(fmaf(acc.y, n, b.y), 0.f),
              (_Float16)fmaxf(fmaf(acc.z, n, b.z), 0.f),
              (_Float16)fmaxf(fmaf(acc.w, n, b.w), 0.f)};
  reinterpret_cast<half4v*>(out)[(size_t)node * 64 + lane] = r;
}

// pull aggregation, C=128: one wave/node, lane owns 2 ch; fp32 out (d_out)
__global__ __launch_bounds__(256) void k_agg128(
    const _Float16* __restrict__ h, const int* __restrict__ rowptr,
    const int* __restrict__ colidx, const float* __restrict__ nd,
    const float* __restrict__ bias, float* __restrict__ out, int N) {
  int node = blockIdx.x * 4 + (threadIdx.x >> 6);
  int lane = threadIdx.x & 63;
  if (node >= N) return;
  const half2v* hv = reinterpret_cast<const half2v*>(h);
  half2v hs = hv[(size_t)node * 64 + lane]; // self-loop
  float2 acc;
  acc.x = (float)hs[0]; acc.y = (float)hs[1];
  int e0 = rowptr[node], e1 = rowptr[node + 1];
  int e = e0;
  for (; e + 7 < e1; e += 8) {
    int si[8];
#pragma unroll
    for (int i = 0; i < 8; ++i) si[i] = colidx[e + i];
    half2v v[8];
#pragma unroll
    for (int i = 0; i < 8; ++i) v[i] = hv[(size_t)si[i] * 64 + lane];
#pragma unroll
    for (int i = 0; i < 8; ++i) {
      acc.x += (float)v[i][0]; acc.y += (float)v[i][1];
    }
  }
  for (; e < e1; ++e) {
    half2v v0 = hv[(size_t)colidx[e] * 64 + lane];
    acc.x += (float)v0[0]; acc.y += (float)v0[1];
  }
  float n = nd[node];
  float2 b = reinterpret_cast<const float2*>(bias)[lane];
  float2 r;
  r.x = fmaxf(fmaf(acc.x, n, b.x), 0.f);
  r.y = fmaxf(fmaf(acc.y, n, b.y), 0.f);
  reinterpret_cast<float2*>(out)[(size_t)node * 64 + lane] = r;
}

extern "C" void kernel_launch(void* const* d_in, const int* in_sizes, int n_in,
                              void* d_out, int out_size, void* d_ws, size_t ws_size,
                              hipStream_t stream) {
  const float* feats = (const float*)d_in[0];
  const int* src = (const int*)d_in[1];
  const int* dst = (const int*)d_in[2];
  const float* W0 = (const float*)d_in[3];
  const float* b0 = (const float*)d_in[4];
  const float* W1 = (const float*)d_in[5];
  const float* b1 = (const float*)d_in[6];
  float* out = (float*)d_out;

  const int IN_CH = 256, HID = 256, OUT_CH = 128;
  int N = in_sizes[0] / IN_CH;
  int E = in_sizes[1];
  int W = (N + NSLAB - 1) / NSLAB;    // 6250 (<= MAXW)
  int CE = (E + NCHUNK - 1) / NCHUNK; // 25000

  char* ws = (char*)d_ws;
  size_t off = 0;
  auto alloc = [&](size_t bytes) -> void* {
    void* p = ws + off;
    off += (bytes + 255) & ~(size_t)255;
    return p;
  };
  _Float16* h0 = (_Float16*)alloc((size_t)N * HID * 2); // layer-0 GEMM out
  _Float16* x1 = (_Float16*)alloc((size_t)N * HID * 2); // layer-0 agg out
  float* nsrc   = (float*)alloc((size_t)N * 4);
  float* ndst   = (float*)alloc((size_t)N * 4);
  unsigned* cntO = (unsigned*)alloc((size_t)NCHUNK * N * 4); // per-chunk odeg
  unsigned* cntI = (unsigned*)alloc((size_t)NCHUNK * N * 4); // per-chunk ideg
  int*   rowptr = (int*)alloc((size_t)(N + 1) * 4);
  int* cursor32 = (int*)alloc((size_t)NCHUNK * N * 4); // per-chunk bases (RO)
  int*   colidx = (int*)alloc((size_t)E * 4);
  int*   bsums  = (int*)alloc(1024);
  short* w0h    = (short*)alloc((size_t)HID * IN_CH * 2);
  short* w0l    = (short*)alloc((size_t)HID * IN_CH * 2);
  short* w1h    = (short*)alloc((size_t)OUT_CH * HID * 2);
  short* w1l    = (short*)alloc((size_t)OUT_CH * HID * 2);
  _Float16* h1  = h0; // reuse: h0 dead after layer-0 agg

  int nbN = (N + 255) / 256;
  k_histlds<<<NSLAB * NCHUNK, 256, 0, stream>>>(src, dst, cntO, cntI, W, CE, N, E);
  k_scan1_norm<<<nbN, 256, 0, stream>>>(cntO, cntI, rowptr, bsums, nsrc, ndst, N);
  k_scan23<<<nbN, 256, 0, stream>>>(rowptr, cursor32, bsums, cntI, nbN, N, E);
  k_fill_lds<<<NSLAB * NCHUNK, 256, 0, stream>>>(src, dst, cursor32, colidx, W, CE, N, E);

  k_wsplit2<<<(IN_CH * HID + HID * OUT_CH) / 256, 256, 0, stream>>>(
      W0, w0h, w0l, W1, w1h, w1l);

  int gm = (N + 63) / 64;
  k_gemm_mfma<256, float><<<gm, 256, 0, stream>>>(feats, w0h, w0l, nsrc, h0, N);
  k_agg256<<<(N + 3) / 4, 256, 0, stream>>>(h0, rowptr, colidx, ndst, b0, x1, N);

  k_gemm_mfma<128, _Float16><<<gm, 256, 0, stream>>>(x1, w1h, w1l, nsrc, h1, N);
  k_agg128<<<(N + 3) / 4, 256, 0, stream>>>(h1, rowptr, colidx, ndst, b1, out, N);
}